// Round 1
// baseline (209.193 us; speedup 1.0000x reference)
//
#include <hip/hip_runtime.h>
#include <cstddef>

// SNN collapse: alpha = expf(-1/0.005) = expf(-200) == 0.0f in fp32, so
// LIF(spiking) == floor(relu(x)) elementwise and LIF(readout) == identity.
// (Verified R1-R3: absmax 0.0.) Per-image feed-forward CNN, fully fused,
// one block per image, intermediates in LDS (t1 in bf16: values are small
// non-negative integers, exact in bf16).
//
// R4: packed fp32 math (v_pk_fma_f32) — accumulate channel PAIRS as
// <2 x float> with splatted activations; halves conv VALU instruction count.
// R5: latency-stall attack (accumulation order unchanged -> still bit-exact):
//   - stage 2/3: 2-deep software pipeline over ci (named pA/pB, static
//     indexing) — next patch's ds_reads issue before current compute, so
//     the lgkmcnt wait overlaps 144 pk_fma instead of stalling each iter.
//   - stage 2: stage raw uints, unpack at compute time (wait lands late).
//   - stage 1: all 8 float4 loads hoisted ahead of compute (8-deep VMEM).
//   - LDS zero-init: borders only (~1.6K entries vs 7.2K full) — interior
//     is overwritten before any read.
// launch_bounds(256,4): grid is 1024 blocks = 4/CU, >4 occupancy is useless.

typedef __attribute__((ext_vector_type(2))) float f2;

__device__ __forceinline__ f2 splat(float v) { f2 r; r.x = v; r.y = v; return r; }
__device__ __forceinline__ float bf_lo(unsigned int u) {
    union { unsigned int i; float f; } c; c.i = u << 16; return c.f;
}
__device__ __forceinline__ float bf_hi(unsigned int u) {
    union { unsigned int i; float f; } c; c.i = u & 0xffff0000u; return c.f;
}
__device__ __forceinline__ unsigned short f2bf(float f) {
    union { float f; unsigned int i; } c; c.f = f; return (unsigned short)(c.i >> 16);
}
__device__ __forceinline__ float spk(float a) {   // floor(relu(x))
    return floorf(fmaxf(a, 0.f));
}

__global__ __launch_bounds__(256, 4) void fused_snn(
    const float* __restrict__ x,    // (1024,2,128,128)
    const float* __restrict__ w1,   // (8,2,2,2)
    const float* __restrict__ w2,   // (8,8,3,3)
    const float* __restrict__ w3,   // (8,8,3,3)
    const float* __restrict__ wfc,  // (2,512)
    float* __restrict__ out)        // (1024,2)
{
    __shared__ unsigned short t1[8][34][34];        // conv1 pooled out, bf16, zero-padded: 18.5 KB
    __shared__ __align__(16) float t2[8][18][18];   // conv2 pooled out, fp32, zero-padded: 10.4 KB
    __shared__ float red[8];

    const int n = blockIdx.x;
    const int t = threadIdx.x;

    // ---- border-only zero-init (interior is fully written before any read)
    {
        // t1 rows y=0,33: 8 planes * 2 rows * 34 = 544
        for (int i = t; i < 544; i += 256) {
            int ci = i / 68, rem = i - ci * 68;
            int ysel = rem / 34, xx = rem - ysel * 34;
            t1[ci][ysel ? 33 : 0][xx] = 0;
        }
        // t1 cols x=0,33 for y=1..32: 8 * 2 * 32 = 512
        for (int i = t; i < 512; i += 256) {
            int ci = i >> 6, rem = i & 63;
            int xsel = rem >> 5, yy = (rem & 31) + 1;
            t1[ci][yy][xsel ? 33 : 0] = 0;
        }
        // t2 rows y=0,17: 8 * 2 * 18 = 288
        for (int i = t; i < 288; i += 256) {
            int ci = i / 36, rem = i - ci * 36;
            int ysel = rem / 18, xx = rem - ysel * 18;
            t2[ci][ysel ? 17 : 0][xx] = 0.f;
        }
        // t2 cols x=0,17 for y=1..16: 8 * 2 * 16 = 256 (exactly 1/thread)
        {
            int ci = t >> 5, rem = t & 31;
            int xsel = rem >> 4, yy = (rem & 15) + 1;
            t2[ci][yy][xsel ? 17 : 0] = 0.f;
        }
    }

    // conv1 weights as co-pairs: wp1[co2][j] = (w1[2co2][j], w1[2co2+1][j]), j = c*4+kh*2+kw
    f2 wp1[4][8];
#pragma unroll
    for (int co2 = 0; co2 < 4; ++co2)
#pragma unroll
        for (int j = 0; j < 8; ++j) {
            wp1[co2][j].x = w1[(2 * co2) * 8 + j];       // uniform -> scalar loads
            wp1[co2][j].y = w1[(2 * co2 + 1) * 8 + j];
        }
    __syncthreads();

    // ---------------- stage 1: conv1(2->8,k2,s2) + floor(relu) + maxpool2 -> t1
    {
        const float* xb = x + (size_t)n * (2 * 128 * 128);
#pragma unroll 2
        for (int k = 0; k < 4; ++k) {
            int i = (k << 8) + t;          // pooled pixel 0..1023
            int py = i >> 5, px = i & 31;  // consecutive t -> consecutive px: coalesced float4

            // hoist all 8 row loads (rows 4py+0..3, both channels) -> 8-deep VMEM pipe
            float4 v[2][4];
#pragma unroll
            for (int c = 0; c < 2; ++c)
#pragma unroll
                for (int rr = 0; rr < 4; ++rr)
                    v[c][rr] = *reinterpret_cast<const float4*>(
                        xb + (c * 128 + 4 * py + rr) * 128 + 4 * px);

            f2 r2[4];
#pragma unroll
            for (int co2 = 0; co2 < 4; ++co2) r2[co2] = splat(0.f);  // floor(relu)>=0

#pragma unroll
            for (int half = 0; half < 2; ++half) {          // pooled-window row pair (oy)
                float p[2][2][4];                           // [c][kh][x]
#pragma unroll
                for (int c = 0; c < 2; ++c)
#pragma unroll
                    for (int r = 0; r < 2; ++r) {
                        float4 w = v[c][2 * half + r];
                        p[c][r][0] = w.x; p[c][r][1] = w.y; p[c][r][2] = w.z; p[c][r][3] = w.w;
                    }
#pragma unroll
                for (int ox = 0; ox < 2; ++ox)
#pragma unroll
                for (int co2 = 0; co2 < 4; ++co2) {
                    f2 a = splat(0.f);
#pragma unroll
                    for (int c = 0; c < 2; ++c)
#pragma unroll
                    for (int kh = 0; kh < 2; ++kh)
#pragma unroll
                    for (int kw = 0; kw < 2; ++kw)
                        a += splat(p[c][kh][2 * ox + kw]) * wp1[co2][c * 4 + kh * 2 + kw];
                    r2[co2].x = fmaxf(r2[co2].x, spk(a.x));
                    r2[co2].y = fmaxf(r2[co2].y, spk(a.y));
                }
            }
#pragma unroll
            for (int co2 = 0; co2 < 4; ++co2) {
                t1[2 * co2 + 0][py + 1][px + 1] = f2bf(r2[co2].x);
                t1[2 * co2 + 1][py + 1][px + 1] = f2bf(r2[co2].y);
            }
        }
    }
    __syncthreads();

    // ---------------- stage 2: conv2(3x3,p1) + floor(relu) + maxpool2 -> t2
    {
        const int py = t >> 4, px = t & 15;   // pooled pixel; all 8 co per thread
        f2 acc[4][2][2];                      // co-pairs
#pragma unroll
        for (int i = 0; i < 16; ++i) (&acc[0][0][0])[i] = splat(0.f);

        // patch staged as raw uints: ds_read -> (later) unpack at compute time
        auto load2 = [&](unsigned int (&u)[4][2], int ci) {
#pragma unroll
            for (int r = 0; r < 4; ++r) {
                const unsigned int* rp = (const unsigned int*)&t1[ci][2 * py + r][0];
                u[r][0] = rp[px];        // elements 2px, 2px+1 (row base uint-aligned)
                u[r][1] = rp[px + 1];    // elements 2px+2, 2px+3
            }
        };
        auto comp2 = [&](unsigned int (&u)[4][2], int ci) {
            float p[4][4];
#pragma unroll
            for (int r = 0; r < 4; ++r) {
                p[r][0] = bf_lo(u[r][0]); p[r][1] = bf_hi(u[r][0]);
                p[r][2] = bf_lo(u[r][1]); p[r][3] = bf_hi(u[r][1]);
            }
#pragma unroll
            for (int co2 = 0; co2 < 4; ++co2) {
                f2 wv[9];                      // uniform addresses -> scalar loads
#pragma unroll
                for (int j = 0; j < 9; ++j) {
                    wv[j].x = w2[((2 * co2 + 0) * 8 + ci) * 9 + j];
                    wv[j].y = w2[((2 * co2 + 1) * 8 + ci) * 9 + j];
                }
#pragma unroll
                for (int oy = 0; oy < 2; ++oy)
#pragma unroll
                for (int ox = 0; ox < 2; ++ox) {
                    f2 a = acc[co2][oy][ox];
#pragma unroll
                    for (int kh = 0; kh < 3; ++kh)
#pragma unroll
                    for (int kw = 0; kw < 3; ++kw)
                        a += splat(p[oy + kh][ox + kw]) * wv[kh * 3 + kw];
                    acc[co2][oy][ox] = a;
                }
            }
        };

        // 2-deep software pipeline over ci: next patch reads in flight during compute
        unsigned int uA[4][2], uB[4][2];
        load2(uA, 0);
#pragma unroll 1
        for (int ci = 0; ci < 8; ci += 2) {
            load2(uB, ci + 1);
            comp2(uA, ci);
            if (ci < 6) load2(uA, ci + 2);
            comp2(uB, ci + 1);
        }

#pragma unroll
        for (int co2 = 0; co2 < 4; ++co2) {
            float mx = 0.f, my = 0.f;
#pragma unroll
            for (int oy = 0; oy < 2; ++oy)
#pragma unroll
            for (int ox = 0; ox < 2; ++ox) {
                mx = fmaxf(mx, spk(acc[co2][oy][ox].x));
                my = fmaxf(my, spk(acc[co2][oy][ox].y));
            }
            t2[2 * co2 + 0][py + 1][px + 1] = mx;
            t2[2 * co2 + 1][py + 1][px + 1] = my;
        }
    }
    __syncthreads();

    // ------- stage 3: conv3(3x3,p1) + floor(relu) + maxpool2 + FC(512->2) -------
    {
        const int co2 = __builtin_amdgcn_readfirstlane(t >> 6);  // wave-uniform: co pair {2co2, 2co2+1}
        const int l = t & 63;
        const int py = l >> 3, px = l & 7;

        f2 acc[2][2];                         // cc in vector lanes
#pragma unroll
        for (int i = 0; i < 4; ++i) (&acc[0][0])[i] = splat(0.f);

        auto load3 = [&](float2 (&p)[4][2], int ci) {
#pragma unroll
            for (int r = 0; r < 4; ++r) {
                const float2* row = reinterpret_cast<const float2*>(&t2[ci][2 * py + r][0]);
                p[r][0] = row[px];
                p[r][1] = row[px + 1];
            }
        };
        auto comp3 = [&](float2 (&pp)[4][2], int ci) {
            float p[4][4];
#pragma unroll
            for (int r = 0; r < 4; ++r) {
                p[r][0] = pp[r][0].x; p[r][1] = pp[r][0].y;
                p[r][2] = pp[r][1].x; p[r][3] = pp[r][1].y;
            }
            f2 wv[9];                          // co2 wave-uniform -> scalar loads
#pragma unroll
            for (int j = 0; j < 9; ++j) {
                wv[j].x = w3[((2 * co2 + 0) * 8 + ci) * 9 + j];
                wv[j].y = w3[((2 * co2 + 1) * 8 + ci) * 9 + j];
            }
#pragma unroll
            for (int oy = 0; oy < 2; ++oy)
#pragma unroll
            for (int ox = 0; ox < 2; ++ox) {
                f2 a = acc[oy][ox];
#pragma unroll
                for (int kh = 0; kh < 3; ++kh)
#pragma unroll
                for (int kw = 0; kw < 3; ++kw)
                    a += splat(p[oy + kh][ox + kw]) * wv[kh * 3 + kw];
                acc[oy][ox] = a;
            }
        };

        float2 pA[4][2], pB[4][2];
        load3(pA, 0);
#pragma unroll 1
        for (int ci = 0; ci < 8; ci += 2) {
            load3(pB, ci + 1);
            comp3(pA, ci);
            if (ci < 6) load3(pA, ci + 2);
            comp3(pB, ci + 1);
        }

        // pool + floor + FC partials; flattened feature o = co*64 + l
        float mx = 0.f, my = 0.f;
#pragma unroll
        for (int oy = 0; oy < 2; ++oy)
#pragma unroll
        for (int ox = 0; ox < 2; ++ox) {
            mx = fmaxf(mx, spk(acc[oy][ox].x));
            my = fmaxf(my, spk(acc[oy][ox].y));
        }
        int o0 = (2 * co2 + 0) * 64 + l;
        int o1 = (2 * co2 + 1) * 64 + l;
        float p0 = mx * wfc[o0] + my * wfc[o1];          // lanes consecutive -> coalesced
        float p1 = mx * wfc[512 + o0] + my * wfc[512 + o1];

#pragma unroll
        for (int off = 32; off > 0; off >>= 1) {
            p0 += __shfl_down(p0, off);
            p1 += __shfl_down(p1, off);
        }
        if (l == 0) { red[co2 * 2 + 0] = p0; red[co2 * 2 + 1] = p1; }
    }
    __syncthreads();

    if (t == 0) {
        out[n * 2 + 0] = red[0] + red[2] + red[4] + red[6];
        out[n * 2 + 1] = red[1] + red[3] + red[5] + red[7];
    }
}

extern "C" void kernel_launch(void* const* d_in, const int* in_sizes, int n_in,
                              void* d_out, int out_size, void* d_ws, size_t ws_size,
                              hipStream_t stream) {
    const float* x   = (const float*)d_in[0];
    const float* w1  = (const float*)d_in[1];
    const float* w2  = (const float*)d_in[2];
    const float* w3  = (const float*)d_in[3];
    const float* wfc = (const float*)d_in[4];
    float* outp = (float*)d_out;

    fused_snn<<<1024, 256, 0, stream>>>(x, w1, w2, w3, wfc, outp);
}